// Round 8
// baseline (644.813 us; speedup 1.0000x reference)
//
#include <hip/hip_runtime.h>
#include <hip/hip_bf16.h>
#include <math.h>

#define Tn 100
#define Bn 2048

typedef int v2i __attribute__((ext_vector_type(2)));

__device__ __forceinline__ float sp_f(float x) {
    // jax.nn.softplus(x) = max(x,0) + log1p(exp(-|x|))
    float e = __expf(-fabsf(x));
    return fmaxf(x, 0.f) + __logf(1.f + e);
}
__device__ __forceinline__ float clamp6(float x) {
    return fminf(fmaxf(x, -6.f), 6.f);
}
// DPP cross-lane (pure VALU).
__device__ __forceinline__ float dpp_xor1(float x) {
    return __int_as_float(__builtin_amdgcn_mov_dpp(__float_as_int(x), 0xB1, 0xF, 0xF, 1));
}
__device__ __forceinline__ float dpp_xor2(float x) {
    return __int_as_float(__builtin_amdgcn_mov_dpp(__float_as_int(x), 0x4E, 0xF, 0xF, 1));
}
__device__ __forceinline__ float dpp_hmirror(float x) {   // == xor4 for quad-uniform
    return __int_as_float(__builtin_amdgcn_mov_dpp(__float_as_int(x), 0x141, 0xF, 0xF, 1));
}
__device__ __forceinline__ float dpp_ror8(float x) {      // == xor8 for 8-uniform
    return __int_as_float(__builtin_amdgcn_mov_dpp(__float_as_int(x), 0x128, 0xF, 0xF, 1));
}
template <int OFF>
__device__ __forceinline__ float swz(float x) {
    return __int_as_float(__builtin_amdgcn_ds_swizzle(__float_as_int(x), OFF));
}
__device__ __forceinline__ float xor16_sum(float x) {
#if __has_builtin(__builtin_amdgcn_permlane16_swap)
    v2i r = __builtin_amdgcn_permlane16_swap(__float_as_int(x), __float_as_int(x), false, false);
    return __int_as_float(r[0]) + __int_as_float(r[1]);
#else
    return x + swz<0x401F>(x);
#endif
}
__device__ __forceinline__ float other_half(float x) {
#if __has_builtin(__builtin_amdgcn_permlane32_swap)
    v2i r = __builtin_amdgcn_permlane32_swap(__float_as_int(x), __float_as_int(x), false, false);
    return (__int_as_float(r[0]) + __int_as_float(r[1])) - x;
#else
    return __shfl_xor(x, 32);
#endif
}

// ---------------------------------------------------------------- encoder
// Weights read DIRECTLY from global with wave-uniform, compile-time indices
// -> compiler selects s_load (scalar pipe, K$), freeing VALU/LDS pipes.
#define ENC_LOAD(buf, base)                                                   \
    _Pragma("unroll")                                                         \
    for (int i = 0; i < 5; ++i) buf[i] = *(const float2*)(x + (base) + 2 * i);
#define ENC_COMP(buf, base)                                                   \
    _Pragma("unroll")                                                         \
    for (int i = 0; i < 5; ++i) {                                             \
        float vx = buf[i].x, vy = buf[i].y;                                   \
        _Pragma("unroll")                                                     \
        for (int j = 0; j < 30; ++j)                                          \
            h1[j] = fmaf(vx, eW1[(base + 2 * i) * 30 + j], h1[j]);            \
        _Pragma("unroll")                                                     \
        for (int j = 0; j < 30; ++j)                                          \
            h1[j] = fmaf(vy, eW1[(base + 2 * i + 1) * 30 + j], h1[j]);        \
    }

__global__ __launch_bounds__(256) void enc_kernel(
    const float* __restrict__ xs,
    const float* __restrict__ eW1, const float* __restrict__ eb1,
    const float* __restrict__ eW2, const float* __restrict__ eb2,
    const float* __restrict__ eW3, const float* __restrict__ eb3,
    float* __restrict__ ctx, float* __restrict__ qm, float* __restrict__ qs)
{
    int gid = blockIdx.x * 256 + threadIdx.x;          // = tt*Bn + b
    const float* x = xs + (size_t)gid * 150;

    float h1[30];
#pragma unroll
    for (int j = 0; j < 30; ++j) h1[j] = eb1[j];

    float2 A[5], Bf[5];
    ENC_LOAD(A, 0)
    ENC_LOAD(Bf, 10)
    int fb = 0;
#pragma unroll 1
    for (int it = 0; it < 6; ++it) {
        ENC_COMP(A, fb)
        ENC_LOAD(A, fb + 20)
        ENC_COMP(Bf, fb + 10)
        ENC_LOAD(Bf, fb + 30)
        fb += 20;
    }
    ENC_COMP(A, 120)
    ENC_LOAD(A, 140)
    ENC_COMP(Bf, 130)
    ENC_COMP(A, 140)

#pragma unroll
    for (int j = 0; j < 30; ++j) h1[j] = sp_f(h1[j]);

    float h2[30];
#pragma unroll
    for (int j = 0; j < 30; ++j) h2[j] = eb2[j];
#pragma unroll
    for (int j1 = 0; j1 < 30; ++j1) {
        float hv = h1[j1];
#pragma unroll
        for (int j = 0; j < 30; ++j) h2[j] = fmaf(hv, eW2[j1 * 30 + j], h2[j]);
    }
#pragma unroll
    for (int j = 0; j < 30; ++j) h2[j] = sp_f(h2[j]);

    float o12 = eb3[12], o13 = eb3[13], o14 = eb3[14];
#pragma unroll
    for (int j2 = 0; j2 < 30; ++j2) {
        o12 = fmaf(h2[j2], eW3[j2 * 15 + 12], o12);
        o13 = fmaf(h2[j2], eW3[j2 * 15 + 13], o13);
        o14 = fmaf(h2[j2], eW3[j2 * 15 + 14], o14);
    }
    float* cp = ctx + (size_t)gid * 3;
    cp[0] = o12; cp[1] = o13; cp[2] = o14;

    if (blockIdx.x < 8) {   // tt == 0
        int b = gid;
        float o[12];
#pragma unroll
        for (int j3 = 0; j3 < 12; ++j3) o[j3] = eb3[j3];
#pragma unroll
        for (int j2 = 0; j2 < 30; ++j2) {
            float hv = h2[j2];
#pragma unroll
            for (int j3 = 0; j3 < 12; ++j3) o[j3] = fmaf(hv, eW3[j2 * 15 + j3], o[j3]);
        }
#pragma unroll
        for (int d = 0; d < 6; ++d) { qm[b * 6 + d] = o[d]; qs[b * 6 + d] = o[6 + d]; }
    }
}

// ------------------------------------------------------------------- SDE scan
// Wave-specialized: 128-thread blocks (2 waves) per chain, grid = 2048.
__global__ __launch_bounds__(128, 4) void scan_kernel(
    const float* __restrict__ ts, const float* __restrict__ dWall,
    const float* __restrict__ fW1, const float* __restrict__ fb1,
    const float* __restrict__ fW2, const float* __restrict__ fb2,
    const float* __restrict__ hW1, const float* __restrict__ hb1,
    const float* __restrict__ hW2, const float* __restrict__ hb2,
    const float* __restrict__ gW1, const float* __restrict__ gb1,
    const float* __restrict__ gW2, const float* __restrict__ gb2,
    const float* __restrict__ ctx,
    const float* __restrict__ qm, const float* __restrict__ qs,
    const float* __restrict__ eps0, const float* __restrict__ pm,
    const float* __restrict__ ps,
    float* __restrict__ zsb, float* __restrict__ acc)
{
    int tid = threadIdx.x;
    int lane = tid & 63;
    int b = blockIdx.x;
    bool isA = tid < 64;

    __shared__ float sRec[99 * 12];   // [0..5]=dW, [6..8]=ctx(k+1), [9]=t, [10]=dt
    __shared__ float exF[2][16];      // fvv[0..5], dfh[0..5]
    __shared__ float exG[2][16];      // {g,rg} pairs

    for (int i = tid; i < 99 * 3; i += 128) {
        int k = i / 3, e = i % 3;
        float2 v = *(const float2*)(dWall + ((size_t)k * Bn + b) * 6 + e * 2);
        *(float2*)&sRec[k * 12 + e * 2] = v;
    }
    for (int i = tid; i < 99 * 3; i += 128) {
        int k = i / 3, e = i % 3;
        sRec[k * 12 + 6 + e] = ctx[((size_t)(k + 1) * Bn + b) * 3 + e];
    }
    for (int i = tid; i < 99; i += 128) {
        float t0 = ts[i], t1 = ts[i + 1];
        sRec[i * 12 + 9]  = t0;
        sRec[i * 12 + 10] = t1 - t0;
        sRec[i * 12 + 11] = 0.f;
    }

    float z[6];
#pragma unroll
    for (int d = 0; d < 6; ++d) {
        float m = qm[b * 6 + d];
        float sq = __expf(clamp6(qs[b * 6 + d]));
        z[d] = fmaf(sq, eps0[b * 6 + d], m);
    }
    if (tid == 0) {
        float* zp = zsb + (size_t)b * 6;
        *(float2*)(zp)     = make_float2(z[0], z[1]);
        *(float2*)(zp + 2) = make_float2(z[2], z[3]);
        *(float2*)(zp + 4) = make_float2(z[4], z[5]);
    }
    if (tid == 64) {
        float klsum = 0.f;
#pragma unroll
        for (int d = 0; d < 6; ++d) {
            float m = qm[b * 6 + d];
            float sq = __expf(clamp6(qs[b * 6 + d]));
            float spz = __expf(clamp6(ps[d]));
            float dm = m - pm[d];
            klsum += __logf(spz / sq) + (sq * sq + dm * dm) / (2.f * spz * spz) - 0.5f;
        }
        atomicAdd(&acc[1], klsum);
    }

    float wl1[10], b1w, wl2[6], fb2v[6], hb2v[6];
    float gwa[4], gwb[4], gw2v[4], gbb[4], gb2v;
    int dL = 0;
    if (isA) {
        bool lower = lane < 32;
        int j = lane & 31;
        int jc = (j < 30) ? j : 29;
        bool jvalid = (j < 30);
#pragma unroll
        for (int i = 0; i < 10; ++i)
            wl1[i] = lower ? fW1[i * 30 + jc] : (i < 7 ? hW1[i * 30 + jc] : 0.f);
        b1w = lower ? fb1[jc] : hb1[jc];
#pragma unroll
        for (int d = 0; d < 6; ++d)
            wl2[d] = jvalid ? (lower ? fW2[jc * 6 + d] : hW2[jc * 6 + d]) : 0.f;
#pragma unroll
        for (int d = 0; d < 6; ++d) { fb2v[d] = fb2[d]; hb2v[d] = hb2[d]; }
    } else {
        int dL8 = lane >> 3;
        dL = (dL8 < 6) ? dL8 : 0;
        int s = lane & 7;
#pragma unroll
        for (int u = 0; u < 4; ++u) {
            int jj = s + 8 * u;
            bool ok = (dL8 < 6) && (jj < 30);
            gwa[u]  = ok ? gW1[dL * 60 + jj] : 0.f;
            gwb[u]  = ok ? gW1[dL * 60 + 30 + jj] : 0.f;
            gw2v[u] = ok ? gW2[dL * 30 + jj] : 0.f;
            gbb[u]  = ok ? gb1[dL * 30 + jj] : 0.f;
        }
        gb2v = gb2[dL];
    }

    __syncthreads();

    float pacc = 0.f;

    for (int k = 0; k < Tn - 1; ++k) {
        int kb = k & 1;
        float4 r0 = *(float4*)&sRec[k * 12];
        float4 r1 = *(float4*)&sRec[k * 12 + 4];
        float4 r2 = *(float4*)&sRec[k * 12 + 8];
        float t = r2.y, dt = r2.z;

        if (isA) {
            float a = fmaf(t, wl1[0], b1w);
#pragma unroll
            for (int i = 0; i < 6; ++i) a = fmaf(z[i], wl1[1 + i], a);
            a = fmaf(r1.z, wl1[7], a);
            a = fmaf(r1.w, wl1[8], a);
            a = fmaf(r2.x, wl1[9], a);
            float hid = sp_f(a);

            float pp[6];
#pragma unroll
            for (int d = 0; d < 6; ++d) pp[d] = hid * wl2[d];
#pragma unroll
            for (int d = 0; d < 6; ++d) pp[d] += dpp_xor1(pp[d]);
#pragma unroll
            for (int d = 0; d < 6; ++d) pp[d] += dpp_xor2(pp[d]);
#pragma unroll
            for (int d = 0; d < 6; ++d) pp[d] += dpp_hmirror(pp[d]);
#pragma unroll
            for (int d = 0; d < 6; ++d) pp[d] += dpp_ror8(pp[d]);
#pragma unroll
            for (int d = 0; d < 6; ++d) pp[d] = xor16_sum(pp[d]);
            float fvv[6], dfh[6];
            bool lower = lane < 32;
#pragma unroll
            for (int d = 0; d < 6; ++d) {
                float oth = other_half(pp[d]);
                float fsum = lower ? pp[d] : oth;
                float hsum = lower ? oth : pp[d];
                fvv[d] = fsum + fb2v[d];
                dfh[d] = fvv[d] - (hsum + hb2v[d]);
            }
            if (lane == 0) {
                *(float4*)&exF[kb][0] = make_float4(fvv[0], fvv[1], fvv[2], fvv[3]);
                *(float4*)&exF[kb][4] = make_float4(fvv[4], fvv[5], dfh[0], dfh[1]);
                *(float4*)&exF[kb][8] = make_float4(dfh[2], dfh[3], dfh[4], dfh[5]);
            }
        } else {
            float zq = z[0];
            zq = (dL == 1) ? z[1] : zq;
            zq = (dL == 2) ? z[2] : zq;
            zq = (dL == 3) ? z[3] : zq;
            zq = (dL == 4) ? z[4] : zq;
            zq = (dL == 5) ? z[5] : zq;
            float ga = 0.f;
#pragma unroll
            for (int u = 0; u < 4; ++u) {
                float pre = fmaf(t, gwa[u], gbb[u]);
                pre = fmaf(zq, gwb[u], pre);
                ga = fmaf(sp_f(pre), gw2v[u], ga);
            }
            ga += dpp_xor1(ga);
            ga += dpp_xor2(ga);
            ga += dpp_hmirror(ga);
            float gacc = ga + gb2v;
            float e = __expf(-gacc);
            float rg = 1.f + e;
            float gval = __builtin_amdgcn_rcpf(rg);
            if ((lane & 7) == 0 && (lane >> 3) < 6)
                *(float2*)&exG[kb][2 * dL] = make_float2(gval, rg);
        }

        __syncthreads();

        float4 f03 = *(float4*)&exF[kb][0];
        float4 f47 = *(float4*)&exF[kb][4];
        float4 d25 = *(float4*)&exF[kb][8];
        float4 e01 = *(float4*)&exG[kb][0];
        float4 e23 = *(float4*)&exG[kb][4];
        float4 e45 = *(float4*)&exG[kb][8];
        float fvv[6] = { f03.x, f03.y, f03.z, f03.w, f47.x, f47.y };
        float dfh[6] = { f47.z, f47.w, d25.x, d25.y, d25.z, d25.w };
        float gl[6]  = { e01.x, e01.z, e23.x, e23.z, e45.x, e45.z };
        float rgv[6] = { e01.y, e01.w, e23.y, e23.w, e45.y, e45.w };

        if (!isA) {
            float s2 = 0.f;
#pragma unroll
            for (int d = 0; d < 6; ++d) {
                float u = dfh[d] * rgv[d];
                s2 = fmaf(u, u, s2);
            }
            pacc = fmaf(0.5f * dt, s2, pacc);
        }

        float dwv[6] = { r0.x, r0.y, r0.z, r0.w, r1.x, r1.y };
#pragma unroll
        for (int d = 0; d < 6; ++d)
            z[d] = fmaf(gl[d], dwv[d], fmaf(fvv[d], dt, z[d]));

        if (tid == 0) {
            float* zp = zsb + ((size_t)(k + 1) * Bn + b) * 6;
            *(float2*)(zp)     = make_float2(z[0], z[1]);
            *(float2*)(zp + 2) = make_float2(z[2], z[3]);
            *(float2*)(zp + 4) = make_float2(z[4], z[5]);
        }
    }
    if (tid == 64) atomicAdd(&acc[2], pacc);
}

// ------------------------------------------------------ decoder + likelihood
// Weights direct-from-global (uniform -> s_load); only the tiny reduction
// scratch stays in LDS.
__global__ __launch_bounds__(256) void dec_kernel(
    const float* __restrict__ zsb, const float* __restrict__ xs,
    const float* __restrict__ dcW1, const float* __restrict__ dcb1,
    const float* __restrict__ dcW2, const float* __restrict__ dcb2,
    const float* __restrict__ dcW3, const float* __restrict__ dcb3,
    float* __restrict__ acc)
{
    int gid = blockIdx.x * 256 + threadIdx.x;       // = t*Bn + b

    const float* tg = xs + (size_t)gid * 150 + 100;   // xs[:,:,-1,:]
    float2 tgv[25];
#pragma unroll
    for (int i = 0; i < 25; ++i) tgv[i] = *(const float2*)(tg + 2 * i);

    const float* zp = zsb + (size_t)gid * 6;
    float zv[6];
#pragma unroll
    for (int i = 0; i < 3; ++i) {
        float2 zv2 = *(const float2*)(zp + 2 * i);
        zv[2 * i] = zv2.x; zv[2 * i + 1] = zv2.y;
    }

    float h1[30];
#pragma unroll
    for (int j = 0; j < 30; ++j) h1[j] = dcb1[j];
#pragma unroll
    for (int i = 0; i < 6; ++i) {
        float zi = zv[i];
#pragma unroll
        for (int j = 0; j < 30; ++j) h1[j] = fmaf(zi, dcW1[i * 30 + j], h1[j]);
    }
#pragma unroll
    for (int j = 0; j < 30; ++j) h1[j] = sp_f(h1[j]);

    float h2[30];
#pragma unroll
    for (int j = 0; j < 30; ++j) h2[j] = dcb2[j];
#pragma unroll
    for (int j1 = 0; j1 < 30; ++j1) {
        float hv = h1[j1];
#pragma unroll
        for (int j = 0; j < 30; ++j) h2[j] = fmaf(hv, dcW2[j1 * 30 + j], h2[j]);
    }
#pragma unroll
    for (int j = 0; j < 30; ++j) h2[j] = sp_f(h2[j]);

    float lpacc = 0.f;
#pragma unroll
    for (int ff = 0; ff < 50; ++ff) {
        float xm0 = dcb3[ff], xm1 = 0.f, xl0 = dcb3[50 + ff], xl1 = 0.f;
#pragma unroll
        for (int j2 = 0; j2 < 30; j2 += 2) {
            xm0 = fmaf(h2[j2],     dcW3[j2 * 100 + ff],         xm0);
            xm1 = fmaf(h2[j2 + 1], dcW3[(j2 + 1) * 100 + ff],   xm1);
            xl0 = fmaf(h2[j2],     dcW3[j2 * 100 + 50 + ff],    xl0);
            xl1 = fmaf(h2[j2 + 1], dcW3[(j2 + 1) * 100 + 50 + ff], xl1);
        }
        float xm = xm0 + xm1;
        float cl = clamp6(xl0 + xl1);
        float tv = (ff & 1) ? tgv[ff >> 1].y : tgv[ff >> 1].x;
        float u = (tv - xm) * __expf(-cl);
        lpacc += -0.5f * u * u - cl - 0.91893853320467274f;
    }
#pragma unroll
    for (int mm = 1; mm <= 32; mm <<= 1) lpacc += __shfl_xor(lpacc, mm);
    __shared__ float red[4];
    if ((threadIdx.x & 63) == 0) red[threadIdx.x >> 6] = lpacc;
    __syncthreads();
    if (threadIdx.x == 0) atomicAdd(&acc[0], red[0] + red[1] + red[2] + red[3]);
}

__global__ void final_kernel(const float* __restrict__ acc, float* __restrict__ out)
{
    out[0] = acc[0] * (1.f / (float)Bn);
    out[1] = (acc[1] + acc[2]) * (1.f / (float)Bn);
}

// --------------------------------------------------------------------- launch
extern "C" void kernel_launch(void* const* d_in, const int* in_sizes, int n_in,
                              void* d_out, int out_size, void* d_ws, size_t ws_size,
                              hipStream_t stream)
{
    const float* xs   = (const float*)d_in[0];
    const float* ts   = (const float*)d_in[1];
    const float* eps0 = (const float*)d_in[2];
    const float* dW   = (const float*)d_in[3];
    const float* eW1  = (const float*)d_in[4];
    const float* eb1  = (const float*)d_in[5];
    const float* eW2  = (const float*)d_in[6];
    const float* eb2  = (const float*)d_in[7];
    const float* eW3  = (const float*)d_in[8];
    const float* eb3  = (const float*)d_in[9];
    const float* dcW1 = (const float*)d_in[10];
    const float* dcb1 = (const float*)d_in[11];
    const float* dcW2 = (const float*)d_in[12];
    const float* dcb2 = (const float*)d_in[13];
    const float* dcW3 = (const float*)d_in[14];
    const float* dcb3 = (const float*)d_in[15];
    const float* fW1  = (const float*)d_in[16];
    const float* fb1  = (const float*)d_in[17];
    const float* fW2  = (const float*)d_in[18];
    const float* fb2  = (const float*)d_in[19];
    const float* hW1  = (const float*)d_in[20];
    const float* hb1  = (const float*)d_in[21];
    const float* hW2  = (const float*)d_in[22];
    const float* hb2  = (const float*)d_in[23];
    const float* gW1  = (const float*)d_in[24];
    const float* gb1  = (const float*)d_in[25];
    const float* gW2  = (const float*)d_in[26];
    const float* gb2  = (const float*)d_in[27];
    const float* pm   = (const float*)d_in[28];
    const float* ps   = (const float*)d_in[29];

    float* ws  = (float*)d_ws;
    float* acc = ws;                    // [0]=S_lp, [1]=S_kl, [2]=S_path
    float* ctx = ws + 16;               // T*B*3 = 614400
    float* qm  = ctx + 614400;          // B*6
    float* qs  = qm + 12288;            // B*6
    float* zs  = qs + 12288;            // T*B*6 = 1228800
    float* out = (float*)d_out;

    hipMemsetAsync(acc, 0, 16 * sizeof(float), stream);
    enc_kernel<<<800, 256, 0, stream>>>(xs, eW1, eb1, eW2, eb2, eW3, eb3, ctx, qm, qs);
    scan_kernel<<<2048, 128, 0, stream>>>(ts, dW, fW1, fb1, fW2, fb2, hW1, hb1,
                                          hW2, hb2, gW1, gb1, gW2, gb2, ctx,
                                          qm, qs, eps0, pm, ps, zs, acc);
    dec_kernel<<<800, 256, 0, stream>>>(zs, xs, dcW1, dcb1, dcW2, dcb2, dcW3, dcb3, acc);
    final_kernel<<<1, 1, 0, stream>>>(acc, out);
}

// Round 9
// 258.008 us; speedup vs baseline: 2.4992x; 2.4992x over previous
//
#include <hip/hip_runtime.h>
#include <hip/hip_bf16.h>
#include <math.h>

#define Tn 100
#define Bn 2048

typedef int v2i __attribute__((ext_vector_type(2)));

__device__ __forceinline__ float sp_f(float x) {
    // jax.nn.softplus(x) = max(x,0) + log1p(exp(-|x|))
    float e = __expf(-fabsf(x));
    return fmaxf(x, 0.f) + __logf(1.f + e);
}
__device__ __forceinline__ float clamp6(float x) {
    return fminf(fmaxf(x, -6.f), 6.f);
}
// DPP cross-lane (pure VALU).
__device__ __forceinline__ float dpp_xor1(float x) {
    return __int_as_float(__builtin_amdgcn_mov_dpp(__float_as_int(x), 0xB1, 0xF, 0xF, 1));
}
__device__ __forceinline__ float dpp_xor2(float x) {
    return __int_as_float(__builtin_amdgcn_mov_dpp(__float_as_int(x), 0x4E, 0xF, 0xF, 1));
}
__device__ __forceinline__ float dpp_hmirror(float x) {   // == xor4 for quad-uniform
    return __int_as_float(__builtin_amdgcn_mov_dpp(__float_as_int(x), 0x141, 0xF, 0xF, 1));
}
__device__ __forceinline__ float dpp_ror8(float x) {      // == xor8 for 8-uniform
    return __int_as_float(__builtin_amdgcn_mov_dpp(__float_as_int(x), 0x128, 0xF, 0xF, 1));
}
template <int OFF>
__device__ __forceinline__ float swz(float x) {
    return __int_as_float(__builtin_amdgcn_ds_swizzle(__float_as_int(x), OFF));
}
__device__ __forceinline__ float xor16_sum(float x) {
#if __has_builtin(__builtin_amdgcn_permlane16_swap)
    v2i r = __builtin_amdgcn_permlane16_swap(__float_as_int(x), __float_as_int(x), false, false);
    return __int_as_float(r[0]) + __int_as_float(r[1]);
#else
    return x + swz<0x401F>(x);
#endif
}
__device__ __forceinline__ float other_half(float x) {
#if __has_builtin(__builtin_amdgcn_permlane32_swap)
    v2i r = __builtin_amdgcn_permlane32_swap(__float_as_int(x), __float_as_int(x), false, false);
    return (__int_as_float(r[0]) + __int_as_float(r[1])) - x;
#else
    return __shfl_xor(x, 32);
#endif
}

// h{a,b}[0..29] += v{a,b} * wrow[0..29]; one LDS read stream serves 2 samples.
__device__ __forceinline__ void row2(float* ha, float* hb, const float* wrow,
                                     float va, float vb) {
#pragma unroll
    for (int q = 0; q < 7; ++q) {
        float4 wv = *(const float4*)(wrow + 4 * q);
        ha[4 * q + 0] = fmaf(va, wv.x, ha[4 * q + 0]);
        hb[4 * q + 0] = fmaf(vb, wv.x, hb[4 * q + 0]);
        ha[4 * q + 1] = fmaf(va, wv.y, ha[4 * q + 1]);
        hb[4 * q + 1] = fmaf(vb, wv.y, hb[4 * q + 1]);
        ha[4 * q + 2] = fmaf(va, wv.z, ha[4 * q + 2]);
        hb[4 * q + 2] = fmaf(vb, wv.z, hb[4 * q + 2]);
        ha[4 * q + 3] = fmaf(va, wv.w, ha[4 * q + 3]);
        hb[4 * q + 3] = fmaf(vb, wv.w, hb[4 * q + 3]);
    }
    float2 wt = *(const float2*)(wrow + 28);
    ha[28] = fmaf(va, wt.x, ha[28]);
    hb[28] = fmaf(vb, wt.x, hb[28]);
    ha[29] = fmaf(va, wt.y, ha[29]);
    hb[29] = fmaf(vb, wt.y, hb[29]);
}
// dual dot30: ra = dot(ha,wrow), rb = dot(hb,wrow)
__device__ __forceinline__ void dot30_2(const float* ha, const float* hb,
                                        const float* wrow, float& ra, float& rb) {
    float a0 = 0.f, a1 = 0.f, b0 = 0.f, b1 = 0.f;
#pragma unroll
    for (int q = 0; q < 7; ++q) {
        float4 wv = *(const float4*)(wrow + 4 * q);
        a0 = fmaf(ha[4 * q + 0], wv.x, a0);
        b0 = fmaf(hb[4 * q + 0], wv.x, b0);
        a1 = fmaf(ha[4 * q + 1], wv.y, a1);
        b1 = fmaf(hb[4 * q + 1], wv.y, b1);
        a0 = fmaf(ha[4 * q + 2], wv.z, a0);
        b0 = fmaf(hb[4 * q + 2], wv.z, b0);
        a1 = fmaf(ha[4 * q + 3], wv.w, a1);
        b1 = fmaf(hb[4 * q + 3], wv.w, b1);
    }
    float2 wt = *(const float2*)(wrow + 28);
    a0 = fmaf(ha[28], wt.x, a0);
    b0 = fmaf(hb[28], wt.x, b0);
    a1 = fmaf(ha[29], wt.y, a1);
    b1 = fmaf(hb[29], wt.y, b1);
    ra = a0 + a1; rb = b0 + b1;
}

// ---------------------------------------------------------------- encoder
// M=2 samples/thread; LDS rows padded to stride 32 (round-7 layout):
// eW1 rows i*32 ; eb1 @4800 ; eW2 rows 4832+j1*32 ; eb2 @5792 ;
// eW3 @5824 (j2*15+j3) ; eb3 @6274.
#define ENC_LOAD2(b0, b1, base)                                               \
    _Pragma("unroll")                                                         \
    for (int i = 0; i < 5; ++i) {                                             \
        b0[i] = *(const float2*)(x0 + (base) + 2 * i);                        \
        b1[i] = *(const float2*)(x1 + (base) + 2 * i);                        \
    }
#define ENC_COMP2(b0, b1, base)                                               \
    _Pragma("unroll")                                                         \
    for (int i = 0; i < 5; ++i) {                                             \
        row2(h1a, h1b, &w[(base + 2 * i) * 32], b0[i].x, b1[i].x);            \
        row2(h1a, h1b, &w[(base + 2 * i + 1) * 32], b0[i].y, b1[i].y);        \
    }

__global__ __launch_bounds__(256) void enc_kernel(
    const float* __restrict__ xs,
    const float* __restrict__ eW1, const float* __restrict__ eb1,
    const float* __restrict__ eW2, const float* __restrict__ eb2,
    const float* __restrict__ eW3, const float* __restrict__ eb3,
    float* __restrict__ ctx, float* __restrict__ qm, float* __restrict__ qs)
{
    __shared__ float w[6292];
    for (int i = threadIdx.x; i < 4500; i += 256) w[(i / 30) * 32 + (i % 30)] = eW1[i];
    if (threadIdx.x < 30) w[4800 + threadIdx.x] = eb1[threadIdx.x];
    for (int i = threadIdx.x; i < 900; i += 256) w[4832 + (i / 30) * 32 + (i % 30)] = eW2[i];
    if (threadIdx.x < 30) w[5792 + threadIdx.x] = eb2[threadIdx.x];
    for (int i = threadIdx.x; i < 450; i += 256) w[5824 + i] = eW3[i];
    if (threadIdx.x < 15) w[6274 + threadIdx.x] = eb3[threadIdx.x];
    __syncthreads();

    int t = threadIdx.x;
    size_t base = (size_t)blockIdx.x * 512;
    size_t s0 = base + t, s1 = base + t + 256;
    const float* x0 = xs + s0 * 150;
    const float* x1 = xs + s1 * 150;

    float h1a[30], h1b[30];
#pragma unroll
    for (int j = 0; j < 30; ++j) { h1a[j] = w[4800 + j]; h1b[j] = h1a[j]; }

    float2 A0[5], A1[5], B0[5], B1[5];
    ENC_LOAD2(A0, A1, 0)
    ENC_LOAD2(B0, B1, 10)
    int fb = 0;
#pragma unroll 1
    for (int it = 0; it < 6; ++it) {
        ENC_COMP2(A0, A1, fb)
        ENC_LOAD2(A0, A1, fb + 20)
        ENC_COMP2(B0, B1, fb + 10)
        ENC_LOAD2(B0, B1, fb + 30)
        fb += 20;
    }
    ENC_COMP2(A0, A1, 120)
    ENC_LOAD2(A0, A1, 140)
    ENC_COMP2(B0, B1, 130)
    ENC_COMP2(A0, A1, 140)

#pragma unroll
    for (int j = 0; j < 30; ++j) { h1a[j] = sp_f(h1a[j]); h1b[j] = sp_f(h1b[j]); }

    float h2a[30], h2b[30];
#pragma unroll
    for (int j = 0; j < 30; ++j) { h2a[j] = w[5792 + j]; h2b[j] = h2a[j]; }
#pragma unroll
    for (int j1 = 0; j1 < 30; ++j1)
        row2(h2a, h2b, &w[4832 + j1 * 32], h1a[j1], h1b[j1]);
#pragma unroll
    for (int j = 0; j < 30; ++j) { h2a[j] = sp_f(h2a[j]); h2b[j] = sp_f(h2b[j]); }

    float oa12 = w[6274 + 12], oa13 = w[6274 + 13], oa14 = w[6274 + 14];
    float ob12 = oa12, ob13 = oa13, ob14 = oa14;
#pragma unroll
    for (int j2 = 0; j2 < 30; ++j2) {
        float w12 = w[5824 + j2 * 15 + 12];
        float w13 = w[5824 + j2 * 15 + 13];
        float w14 = w[5824 + j2 * 15 + 14];
        oa12 = fmaf(h2a[j2], w12, oa12); ob12 = fmaf(h2b[j2], w12, ob12);
        oa13 = fmaf(h2a[j2], w13, oa13); ob13 = fmaf(h2b[j2], w13, ob13);
        oa14 = fmaf(h2a[j2], w14, oa14); ob14 = fmaf(h2b[j2], w14, ob14);
    }
    float* cp0 = ctx + s0 * 3;
    cp0[0] = oa12; cp0[1] = oa13; cp0[2] = oa14;
    float* cp1 = ctx + s1 * 3;
    cp1[0] = ob12; cp1[1] = ob13; cp1[2] = ob14;

    if (blockIdx.x < 4) {   // samples < 2048: tt == 0 -> qz0 stats
        float oa[12], ob[12];
#pragma unroll
        for (int j3 = 0; j3 < 12; ++j3) { oa[j3] = w[6274 + j3]; ob[j3] = oa[j3]; }
#pragma unroll
        for (int j2 = 0; j2 < 30; ++j2) {
            float hva = h2a[j2], hvb = h2b[j2];
#pragma unroll
            for (int j3 = 0; j3 < 12; ++j3) {
                float wv = w[5824 + j2 * 15 + j3];
                oa[j3] = fmaf(hva, wv, oa[j3]);
                ob[j3] = fmaf(hvb, wv, ob[j3]);
            }
        }
#pragma unroll
        for (int d = 0; d < 6; ++d) {
            qm[s0 * 6 + d] = oa[d]; qs[s0 * 6 + d] = oa[6 + d];
            qm[s1 * 6 + d] = ob[d]; qs[s1 * 6 + d] = ob[6 + d];
        }
    }
}

// ------------------------------------------------------------------- SDE scan
// Wave-specialized: 128-thread blocks (2 waves) per chain, grid = 2048.
__global__ __launch_bounds__(128, 4) void scan_kernel(
    const float* __restrict__ ts, const float* __restrict__ dWall,
    const float* __restrict__ fW1, const float* __restrict__ fb1,
    const float* __restrict__ fW2, const float* __restrict__ fb2,
    const float* __restrict__ hW1, const float* __restrict__ hb1,
    const float* __restrict__ hW2, const float* __restrict__ hb2,
    const float* __restrict__ gW1, const float* __restrict__ gb1,
    const float* __restrict__ gW2, const float* __restrict__ gb2,
    const float* __restrict__ ctx,
    const float* __restrict__ qm, const float* __restrict__ qs,
    const float* __restrict__ eps0, const float* __restrict__ pm,
    const float* __restrict__ ps,
    float* __restrict__ zsb, float* __restrict__ acc)
{
    int tid = threadIdx.x;
    int lane = tid & 63;
    int b = blockIdx.x;
    bool isA = tid < 64;

    __shared__ float sRec[99 * 12];   // [0..5]=dW, [6..8]=ctx(k+1), [9]=t, [10]=dt
    __shared__ float exF[2][16];      // fvv[0..5], dfh[0..5]
    __shared__ float exG[2][16];      // {g,rg} pairs

    for (int i = tid; i < 99 * 3; i += 128) {
        int k = i / 3, e = i % 3;
        float2 v = *(const float2*)(dWall + ((size_t)k * Bn + b) * 6 + e * 2);
        *(float2*)&sRec[k * 12 + e * 2] = v;
    }
    for (int i = tid; i < 99 * 3; i += 128) {
        int k = i / 3, e = i % 3;
        sRec[k * 12 + 6 + e] = ctx[((size_t)(k + 1) * Bn + b) * 3 + e];
    }
    for (int i = tid; i < 99; i += 128) {
        float t0 = ts[i], t1 = ts[i + 1];
        sRec[i * 12 + 9]  = t0;
        sRec[i * 12 + 10] = t1 - t0;
        sRec[i * 12 + 11] = 0.f;
    }

    float z[6];
#pragma unroll
    for (int d = 0; d < 6; ++d) {
        float m = qm[b * 6 + d];
        float sq = __expf(clamp6(qs[b * 6 + d]));
        z[d] = fmaf(sq, eps0[b * 6 + d], m);
    }
    if (tid == 0) {
        float* zp = zsb + (size_t)b * 6;
        *(float2*)(zp)     = make_float2(z[0], z[1]);
        *(float2*)(zp + 2) = make_float2(z[2], z[3]);
        *(float2*)(zp + 4) = make_float2(z[4], z[5]);
    }
    if (tid == 64) {
        float klsum = 0.f;
#pragma unroll
        for (int d = 0; d < 6; ++d) {
            float m = qm[b * 6 + d];
            float sq = __expf(clamp6(qs[b * 6 + d]));
            float spz = __expf(clamp6(ps[d]));
            float dm = m - pm[d];
            klsum += __logf(spz / sq) + (sq * sq + dm * dm) / (2.f * spz * spz) - 0.5f;
        }
        atomicAdd(&acc[1], klsum);
    }

    float wl1[10], b1w, wl2[6], fb2v[6], hb2v[6];
    float gwa[4], gwb[4], gw2v[4], gbb[4], gb2v;
    int dL = 0;
    if (isA) {
        bool lower = lane < 32;
        int j = lane & 31;
        int jc = (j < 30) ? j : 29;
        bool jvalid = (j < 30);
#pragma unroll
        for (int i = 0; i < 10; ++i)
            wl1[i] = lower ? fW1[i * 30 + jc] : (i < 7 ? hW1[i * 30 + jc] : 0.f);
        b1w = lower ? fb1[jc] : hb1[jc];
#pragma unroll
        for (int d = 0; d < 6; ++d)
            wl2[d] = jvalid ? (lower ? fW2[jc * 6 + d] : hW2[jc * 6 + d]) : 0.f;
#pragma unroll
        for (int d = 0; d < 6; ++d) { fb2v[d] = fb2[d]; hb2v[d] = hb2[d]; }
    } else {
        int dL8 = lane >> 3;
        dL = (dL8 < 6) ? dL8 : 0;
        int s = lane & 7;
#pragma unroll
        for (int u = 0; u < 4; ++u) {
            int jj = s + 8 * u;
            bool ok = (dL8 < 6) && (jj < 30);
            gwa[u]  = ok ? gW1[dL * 60 + jj] : 0.f;
            gwb[u]  = ok ? gW1[dL * 60 + 30 + jj] : 0.f;
            gw2v[u] = ok ? gW2[dL * 30 + jj] : 0.f;
            gbb[u]  = ok ? gb1[dL * 30 + jj] : 0.f;
        }
        gb2v = gb2[dL];
    }

    __syncthreads();

    float pacc = 0.f;

    for (int k = 0; k < Tn - 1; ++k) {
        int kb = k & 1;
        float4 r0 = *(float4*)&sRec[k * 12];
        float4 r1 = *(float4*)&sRec[k * 12 + 4];
        float4 r2 = *(float4*)&sRec[k * 12 + 8];
        float t = r2.y, dt = r2.z;

        if (isA) {
            float a = fmaf(t, wl1[0], b1w);
#pragma unroll
            for (int i = 0; i < 6; ++i) a = fmaf(z[i], wl1[1 + i], a);
            a = fmaf(r1.z, wl1[7], a);
            a = fmaf(r1.w, wl1[8], a);
            a = fmaf(r2.x, wl1[9], a);
            float hid = sp_f(a);

            float pp[6];
#pragma unroll
            for (int d = 0; d < 6; ++d) pp[d] = hid * wl2[d];
#pragma unroll
            for (int d = 0; d < 6; ++d) pp[d] += dpp_xor1(pp[d]);
#pragma unroll
            for (int d = 0; d < 6; ++d) pp[d] += dpp_xor2(pp[d]);
#pragma unroll
            for (int d = 0; d < 6; ++d) pp[d] += dpp_hmirror(pp[d]);
#pragma unroll
            for (int d = 0; d < 6; ++d) pp[d] += dpp_ror8(pp[d]);
#pragma unroll
            for (int d = 0; d < 6; ++d) pp[d] = xor16_sum(pp[d]);
            float fvv[6], dfh[6];
            bool lower = lane < 32;
#pragma unroll
            for (int d = 0; d < 6; ++d) {
                float oth = other_half(pp[d]);
                float fsum = lower ? pp[d] : oth;
                float hsum = lower ? oth : pp[d];
                fvv[d] = fsum + fb2v[d];
                dfh[d] = fvv[d] - (hsum + hb2v[d]);
            }
            if (lane == 0) {
                *(float4*)&exF[kb][0] = make_float4(fvv[0], fvv[1], fvv[2], fvv[3]);
                *(float4*)&exF[kb][4] = make_float4(fvv[4], fvv[5], dfh[0], dfh[1]);
                *(float4*)&exF[kb][8] = make_float4(dfh[2], dfh[3], dfh[4], dfh[5]);
            }
        } else {
            float zq = z[0];
            zq = (dL == 1) ? z[1] : zq;
            zq = (dL == 2) ? z[2] : zq;
            zq = (dL == 3) ? z[3] : zq;
            zq = (dL == 4) ? z[4] : zq;
            zq = (dL == 5) ? z[5] : zq;
            float ga = 0.f;
#pragma unroll
            for (int u = 0; u < 4; ++u) {
                float pre = fmaf(t, gwa[u], gbb[u]);
                pre = fmaf(zq, gwb[u], pre);
                ga = fmaf(sp_f(pre), gw2v[u], ga);
            }
            ga += dpp_xor1(ga);
            ga += dpp_xor2(ga);
            ga += dpp_hmirror(ga);
            float gacc = ga + gb2v;
            float e = __expf(-gacc);
            float rg = 1.f + e;
            float gval = __builtin_amdgcn_rcpf(rg);
            if ((lane & 7) == 0 && (lane >> 3) < 6)
                *(float2*)&exG[kb][2 * dL] = make_float2(gval, rg);
        }

        __syncthreads();

        float4 f03 = *(float4*)&exF[kb][0];
        float4 f47 = *(float4*)&exF[kb][4];
        float4 d25 = *(float4*)&exF[kb][8];
        float4 e01 = *(float4*)&exG[kb][0];
        float4 e23 = *(float4*)&exG[kb][4];
        float4 e45 = *(float4*)&exG[kb][8];
        float fvv[6] = { f03.x, f03.y, f03.z, f03.w, f47.x, f47.y };
        float dfh[6] = { f47.z, f47.w, d25.x, d25.y, d25.z, d25.w };
        float gl[6]  = { e01.x, e01.z, e23.x, e23.z, e45.x, e45.z };
        float rgv[6] = { e01.y, e01.w, e23.y, e23.w, e45.y, e45.w };

        if (!isA) {
            float s2 = 0.f;
#pragma unroll
            for (int d = 0; d < 6; ++d) {
                float u = dfh[d] * rgv[d];
                s2 = fmaf(u, u, s2);
            }
            pacc = fmaf(0.5f * dt, s2, pacc);
        }

        float dwv[6] = { r0.x, r0.y, r0.z, r0.w, r1.x, r1.y };
#pragma unroll
        for (int d = 0; d < 6; ++d)
            z[d] = fmaf(gl[d], dwv[d], fmaf(fvv[d], dt, z[d]));

        if (tid == 0) {
            float* zp = zsb + ((size_t)(k + 1) * Bn + b) * 6;
            *(float2*)(zp)     = make_float2(z[0], z[1]);
            *(float2*)(zp + 2) = make_float2(z[2], z[3]);
            *(float2*)(zp + 4) = make_float2(z[4], z[5]);
        }
    }
    if (tid == 64) atomicAdd(&acc[2], pacc);
}

// ------------------------------------------------------ decoder + likelihood
// M=2 samples/thread; round-7 LDS layout: dcW1 rows i*32 ; dcb1 @192 ;
// dcW2 rows 224+j1*32 ; dcb2 @1184 ; dcW3T rows 1216+j3*32 ; dcb3 @4416.
#define DEC_TLOAD(b0, b1, base)                                               \
    _Pragma("unroll")                                                         \
    for (int i = 0; i < 5; ++i) {                                             \
        b0[i] = *(const float2*)(tg0 + (base) + 2 * i);                       \
        b1[i] = *(const float2*)(tg1 + (base) + 2 * i);                       \
    }
#define DEC_LCOMP(b0, b1, base)                                               \
    _Pragma("unroll")                                                         \
    for (int i = 0; i < 10; ++i) {                                            \
        int ff = (base) + i;                                                  \
        float dma, dmb, dla, dlb;                                             \
        dot30_2(h2a, h2b, &w[1216 + ff * 32], dma, dmb);                      \
        dot30_2(h2a, h2b, &w[1216 + (50 + ff) * 32], dla, dlb);               \
        float xma = w[4416 + ff] + dma, xmb = w[4416 + ff] + dmb;             \
        float cla = clamp6(w[4416 + 50 + ff] + dla);                          \
        float clb = clamp6(w[4416 + 50 + ff] + dlb);                          \
        float tva = (i & 1) ? b0[i >> 1].y : b0[i >> 1].x;                    \
        float tvb = (i & 1) ? b1[i >> 1].y : b1[i >> 1].x;                    \
        float ua = (tva - xma) * __expf(-cla);                                \
        float ub = (tvb - xmb) * __expf(-clb);                                \
        lpa += -0.5f * ua * ua - cla - 0.91893853320467274f;                  \
        lpb += -0.5f * ub * ub - clb - 0.91893853320467274f;                  \
    }

__global__ __launch_bounds__(256) void dec_kernel(
    const float* __restrict__ zsb, const float* __restrict__ xs,
    const float* __restrict__ dcW1, const float* __restrict__ dcb1,
    const float* __restrict__ dcW2, const float* __restrict__ dcb2,
    const float* __restrict__ dcW3, const float* __restrict__ dcb3,
    float* __restrict__ acc)
{
    __shared__ float w[4516];
    for (int i = threadIdx.x; i < 180; i += 256) w[(i / 30) * 32 + (i % 30)] = dcW1[i];
    if (threadIdx.x < 30) w[192 + threadIdx.x] = dcb1[threadIdx.x];
    for (int i = threadIdx.x; i < 900; i += 256) w[224 + (i / 30) * 32 + (i % 30)] = dcW2[i];
    if (threadIdx.x < 30) w[1184 + threadIdx.x] = dcb2[threadIdx.x];
    for (int i = threadIdx.x; i < 3000; i += 256) {
        int j2 = i / 100, j3 = i % 100;
        w[1216 + j3 * 32 + j2] = dcW3[i];
    }
    for (int i = threadIdx.x; i < 100; i += 256) w[4416 + i] = dcb3[i];
    __syncthreads();

    int t = threadIdx.x;
    size_t base = (size_t)blockIdx.x * 512;
    size_t s0 = base + t, s1 = base + t + 256;

    float za[6], zb[6];
    {
        const float* zp0 = zsb + s0 * 6;
        const float* zp1 = zsb + s1 * 6;
#pragma unroll
        for (int i = 0; i < 3; ++i) {
            float2 v0 = *(const float2*)(zp0 + 2 * i);
            float2 v1 = *(const float2*)(zp1 + 2 * i);
            za[2 * i] = v0.x; za[2 * i + 1] = v0.y;
            zb[2 * i] = v1.x; zb[2 * i + 1] = v1.y;
        }
    }

    float h1a[30], h1b[30];
#pragma unroll
    for (int j = 0; j < 30; ++j) { h1a[j] = w[192 + j]; h1b[j] = h1a[j]; }
#pragma unroll
    for (int i = 0; i < 6; ++i) row2(h1a, h1b, &w[i * 32], za[i], zb[i]);
#pragma unroll
    for (int j = 0; j < 30; ++j) { h1a[j] = sp_f(h1a[j]); h1b[j] = sp_f(h1b[j]); }

    float h2a[30], h2b[30];
#pragma unroll
    for (int j = 0; j < 30; ++j) { h2a[j] = w[1184 + j]; h2b[j] = h2a[j]; }
#pragma unroll
    for (int j1 = 0; j1 < 30; ++j1)
        row2(h2a, h2b, &w[224 + j1 * 32], h1a[j1], h1b[j1]);
#pragma unroll
    for (int j = 0; j < 30; ++j) { h2a[j] = sp_f(h2a[j]); h2b[j] = sp_f(h2b[j]); }

    const float* tg0 = xs + s0 * 150 + 100;   // xs[:,:,-1,:]
    const float* tg1 = xs + s1 * 150 + 100;
    float lpa = 0.f, lpb = 0.f;
    float2 TA0[5], TA1[5], TB0[5], TB1[5];
    DEC_TLOAD(TA0, TA1, 0)
    DEC_TLOAD(TB0, TB1, 10)
    DEC_LCOMP(TA0, TA1, 0)
    DEC_TLOAD(TA0, TA1, 20)
    DEC_LCOMP(TB0, TB1, 10)
    DEC_TLOAD(TB0, TB1, 30)
    DEC_LCOMP(TA0, TA1, 20)
    DEC_TLOAD(TA0, TA1, 40)
    DEC_LCOMP(TB0, TB1, 30)
    DEC_LCOMP(TA0, TA1, 40)

    float lpacc = lpa + lpb;
#pragma unroll
    for (int mm = 1; mm <= 32; mm <<= 1) lpacc += __shfl_xor(lpacc, mm);
    __shared__ float red[4];
    if ((threadIdx.x & 63) == 0) red[threadIdx.x >> 6] = lpacc;
    __syncthreads();
    if (threadIdx.x == 0) atomicAdd(&acc[0], red[0] + red[1] + red[2] + red[3]);
}

__global__ void final_kernel(const float* __restrict__ acc, float* __restrict__ out)
{
    out[0] = acc[0] * (1.f / (float)Bn);
    out[1] = (acc[1] + acc[2]) * (1.f / (float)Bn);
}

// --------------------------------------------------------------------- launch
extern "C" void kernel_launch(void* const* d_in, const int* in_sizes, int n_in,
                              void* d_out, int out_size, void* d_ws, size_t ws_size,
                              hipStream_t stream)
{
    const float* xs   = (const float*)d_in[0];
    const float* ts   = (const float*)d_in[1];
    const float* eps0 = (const float*)d_in[2];
    const float* dW   = (const float*)d_in[3];
    const float* eW1  = (const float*)d_in[4];
    const float* eb1  = (const float*)d_in[5];
    const float* eW2  = (const float*)d_in[6];
    const float* eb2  = (const float*)d_in[7];
    const float* eW3  = (const float*)d_in[8];
    const float* eb3  = (const float*)d_in[9];
    const float* dcW1 = (const float*)d_in[10];
    const float* dcb1 = (const float*)d_in[11];
    const float* dcW2 = (const float*)d_in[12];
    const float* dcb2 = (const float*)d_in[13];
    const float* dcW3 = (const float*)d_in[14];
    const float* dcb3 = (const float*)d_in[15];
    const float* fW1  = (const float*)d_in[16];
    const float* fb1  = (const float*)d_in[17];
    const float* fW2  = (const float*)d_in[18];
    const float* fb2  = (const float*)d_in[19];
    const float* hW1  = (const float*)d_in[20];
    const float* hb1  = (const float*)d_in[21];
    const float* hW2  = (const float*)d_in[22];
    const float* hb2  = (const float*)d_in[23];
    const float* gW1  = (const float*)d_in[24];
    const float* gb1  = (const float*)d_in[25];
    const float* gW2  = (const float*)d_in[26];
    const float* gb2  = (const float*)d_in[27];
    const float* pm   = (const float*)d_in[28];
    const float* ps   = (const float*)d_in[29];

    float* ws  = (float*)d_ws;
    float* acc = ws;                    // [0]=S_lp, [1]=S_kl, [2]=S_path
    float* ctx = ws + 16;               // T*B*3 = 614400
    float* qm  = ctx + 614400;          // B*6
    float* qs  = qm + 12288;            // B*6
    float* zs  = qs + 12288;            // T*B*6 = 1228800
    float* out = (float*)d_out;

    hipMemsetAsync(acc, 0, 16 * sizeof(float), stream);
    enc_kernel<<<400, 256, 0, stream>>>(xs, eW1, eb1, eW2, eb2, eW3, eb3, ctx, qm, qs);
    scan_kernel<<<2048, 128, 0, stream>>>(ts, dW, fW1, fb1, fW2, fb2, hW1, hb1,
                                          hW2, hb2, gW1, gb1, gW2, gb2, ctx,
                                          qm, qs, eps0, pm, ps, zs, acc);
    dec_kernel<<<400, 256, 0, stream>>>(zs, xs, dcW1, dcb1, dcW2, dcb2, dcW3, dcb3, acc);
    final_kernel<<<1, 1, 0, stream>>>(acc, out);
}